// Round 2
// baseline (3427.720 us; speedup 1.0000x reference)
//
#include <hip/hip_runtime.h>
#include <math.h>

typedef unsigned short ushort_t;
typedef __bf16 bf16x8 __attribute__((ext_vector_type(8)));
typedef float f32x4 __attribute__((ext_vector_type(4)));

#define HEADS 16

__device__ __forceinline__ ushort_t f2b(float f) {
    unsigned int u = __float_as_uint(f);
    unsigned int r = (u + 0x7FFFu + ((u >> 16) & 1u)) >> 16;
    return (ushort_t)r;
}

// ---------------------------------------------------------------- copy x -> residual
__global__ __launch_bounds__(256) void copy_kernel(const float* __restrict__ x,
                                                   float* __restrict__ y) {
    int i = blockIdx.x * 256 + threadIdx.x;
    ((float4*)y)[i] = ((const float4*)x)[i];
}

// ---------------------------------------------------------------- LayerNorm: fp32 res -> bf16 h
__global__ __launch_bounds__(256) void ln_kernel(const float* __restrict__ x,
                                                 const float* __restrict__ s,
                                                 const float* __restrict__ b,
                                                 ushort_t* __restrict__ out) {
    int row = blockIdx.x;
    int t = threadIdx.x;
    const float* xr = x + (size_t)row * 1024;
    float4 xv = *(const float4*)(xr + t * 4);
    float sum = xv.x + xv.y + xv.z + xv.w;
    float sq = xv.x * xv.x + xv.y * xv.y + xv.z * xv.z + xv.w * xv.w;
#pragma unroll
    for (int m = 1; m < 64; m <<= 1) {
        sum += __shfl_xor(sum, m);
        sq += __shfl_xor(sq, m);
    }
    __shared__ float red[8];
    int wave = t >> 6, lane = t & 63;
    if (lane == 0) { red[wave] = sum; red[4 + wave] = sq; }
    __syncthreads();
    sum = red[0] + red[1] + red[2] + red[3];
    sq = red[4] + red[5] + red[6] + red[7];
    float mean = sum * (1.0f / 1024.0f);
    float var = sq * (1.0f / 1024.0f) - mean * mean;
    float inv = rsqrtf(var + 1e-5f);
    float4 sv = *(const float4*)(s + t * 4);
    float4 bv = *(const float4*)(b + t * 4);
    unsigned int lo = (unsigned int)f2b((xv.x - mean) * inv * sv.x + bv.x) |
                      ((unsigned int)f2b((xv.y - mean) * inv * sv.y + bv.y) << 16);
    unsigned int hi = (unsigned int)f2b((xv.z - mean) * inv * sv.z + bv.z) |
                      ((unsigned int)f2b((xv.w - mean) * inv * sv.w + bv.w) << 16);
    uint2 o;
    o.x = lo; o.y = hi;
    *(uint2*)(out + (size_t)row * 1024 + t * 4) = o;
}

// ---------------------------------------------------------------- GEMM (bf16 A [M,K], fp32 B [K,N])
// MODE 0: QKV scatter -> q[b,h,n,d], k[b,h,n,d], vt[b,h,d,n] (bf16)
// MODE 1: res[m,n] += C + bias[n]   (fp32 residual update)
// MODE 2: outb[m,n] = bf16(gelu(C + bias[n]))
template <int MODE>
__global__ __launch_bounds__(256) void gemm_kernel(
    const ushort_t* __restrict__ A, const float* __restrict__ Bw,
    const float* __restrict__ bias, float* __restrict__ res,
    ushort_t* __restrict__ outb, ushort_t* __restrict__ qo,
    ushort_t* __restrict__ ko, ushort_t* __restrict__ vto, int K, int N) {
    // frag-slot LDS layout: slot = (tile16*4 + kchunk)*16 + lane15, 8 bf16 per slot
    __shared__ __align__(16) ushort_t sA[128 * 32];
    __shared__ __align__(16) ushort_t sB[128 * 32];
    const int t = threadIdx.x;
    const int lane = t & 63;
    const int wave = t >> 6;
    const int l15 = lane & 15;
    const int quad = lane >> 4;
    const int wm = wave >> 1, wn = wave & 1;
    const int m0 = blockIdx.y * 128;
    const int n0 = blockIdx.x * 128;

    f32x4 acc[4][4];
#pragma unroll
    for (int i = 0; i < 4; i++)
#pragma unroll
        for (int j = 0; j < 4; j++) acc[i][j] = (f32x4){0.f, 0.f, 0.f, 0.f};

    const int nkt = K >> 5;
    for (int kt = 0; kt < nkt; kt++) {
        const int k0 = kt * 32;
        __syncthreads();
        // stage A (bf16, 16B vector copies into frag-slot order)
#pragma unroll
        for (int p = 0; p < 2; p++) {
            int u = t + p * 256;
            int row = u >> 2, ch = u & 3;
            uint4 v = *(const uint4*)(A + (size_t)(m0 + row) * K + k0 + ch * 8);
            *(uint4*)(sA + (((row >> 4) * 4 + ch) * 16 + (row & 15)) * 8) = v;
        }
        // stage B: fp32 [K,N] -> bf16 [n][k] frag-slot (transpose + convert)
#pragma unroll
        for (int p = 0; p < 4; p++) {
            int u = t + p * 256;
            int krow = u >> 5;
            int nc = (u & 31) << 2;
            float4 v = *(const float4*)(Bw + (size_t)(k0 + krow) * N + n0 + nc);
            const float* vf = (const float*)&v;
#pragma unroll
            for (int i2 = 0; i2 < 4; i2++) {
                int n = nc + i2;
                sB[(((n >> 4) * 4 + (krow >> 3)) * 16 + (n & 15)) * 8 + (krow & 7)] =
                    f2b(vf[i2]);
            }
        }
        __syncthreads();
        bf16x8 af[4], bf[4];
#pragma unroll
        for (int i = 0; i < 4; i++) {
            af[i] = ((const bf16x8*)sA)[((wm * 4 + i) * 4 + quad) * 16 + l15];
            bf[i] = ((const bf16x8*)sB)[((wn * 4 + i) * 4 + quad) * 16 + l15];
        }
#pragma unroll
        for (int mi = 0; mi < 4; mi++)
#pragma unroll
            for (int ni = 0; ni < 4; ni++)
                acc[mi][ni] = __builtin_amdgcn_mfma_f32_16x16x32_bf16(
                    af[mi], bf[ni], acc[mi][ni], 0, 0, 0);
    }
    // epilogue: C/D layout row = quad*4+r, col = l15
#pragma unroll
    for (int mi = 0; mi < 4; mi++) {
#pragma unroll
        for (int ni = 0; ni < 4; ni++) {
#pragma unroll
            for (int r = 0; r < 4; r++) {
                int mg = m0 + wm * 64 + mi * 16 + quad * 4 + r;
                int ng = n0 + wn * 64 + ni * 16 + l15;
                float c = acc[mi][ni][r];
                if (MODE == 1) {
                    size_t idx = (size_t)mg * N + ng;
                    res[idx] = c + bias[ng] + res[idx];
                } else if (MODE == 2) {
                    float vv = c + bias[ng];
                    float g = 0.5f * vv * (1.0f + erff(vv * 0.70710678118654752f));
                    outb[(size_t)mg * N + ng] = f2b(g);
                } else {
                    int qkv = ng >> 10;
                    int rem = ng & 1023;
                    int hh = rem >> 6;
                    int dd = rem & 63;
                    int bb = mg >> 10;
                    int seq = mg & 1023;
                    ushort_t val = f2b(c);
                    if (qkv == 0)
                        qo[((size_t)(bb * HEADS + hh) * 1024 + seq) * 64 + dd] = val;
                    else if (qkv == 1)
                        ko[((size_t)(bb * HEADS + hh) * 1024 + seq) * 64 + dd] = val;
                    else
                        vto[((size_t)(bb * HEADS + hh) * 64 + dd) * 1024 + seq] = val;
                }
            }
        }
    }
}

// ---------------------------------------------------------------- flash attention
// q,k: [b,h,1024,64] bf16; vt: [b,h,64,1024] bf16; o: [b,1024,1024] bf16 (seq-major, feat=h*64+d)
__global__ __launch_bounds__(256) void attn_kernel(const ushort_t* __restrict__ q,
                                                   const ushort_t* __restrict__ k,
                                                   const ushort_t* __restrict__ vt,
                                                   ushort_t* __restrict__ o) {
    __shared__ __align__(16) ushort_t sK[64 * 72];
    __shared__ __align__(16) ushort_t sV[64 * 72];
    __shared__ __align__(16) ushort_t sP[4 * 16 * 72];
    const int t = threadIdx.x;
    const int lane = t & 63;
    const int w = t >> 6;
    const int l15 = lane & 15;
    const int quad = lane >> 4;
    const int qt = blockIdx.x;
    const int bh = blockIdx.y;

    // Q fragments (A-layout): rows w*16+l15, dh chunks quad*8 (+0/+32)
    bf16x8 aq[2];
    const ushort_t* qbase = q + ((size_t)bh * 1024 + qt * 64 + w * 16 + l15) * 64;
    aq[0] = *(const bf16x8*)(qbase + quad * 8);
    aq[1] = *(const bf16x8*)(qbase + 32 + quad * 8);

    float m_old[4], l_sum[4];
    f32x4 oacc[4];
#pragma unroll
    for (int r = 0; r < 4; r++) { m_old[r] = -1e30f; l_sum[r] = 0.f; }
#pragma unroll
    for (int i = 0; i < 4; i++) oacc[i] = (f32x4){0.f, 0.f, 0.f, 0.f};

    const float scale = 0.03125f;  // 1024^-0.5 (reference scales by full D!)

    for (int kt = 0; kt < 16; kt++) {
        __syncthreads();
        // stage K tile [64 keys][64 dh] and Vt tile [64 dh][64 keys]
#pragma unroll
        for (int p = 0; p < 2; p++) {
            int u = t + p * 256;
            int row = u >> 3, ch = u & 7;
            uint4 v = *(const uint4*)(k + ((size_t)bh * 1024 + kt * 64 + row) * 64 + ch * 8);
            *(uint4*)(sK + row * 72 + ch * 8) = v;
            uint4 v2 = *(const uint4*)(vt + ((size_t)bh * 64 + row) * 1024 + kt * 64 + ch * 8);
            *(uint4*)(sV + row * 72 + ch * 8) = v2;
        }
        __syncthreads();
        // S = Q K^T * scale (per wave: 16 q-rows x 64 keys)
        f32x4 s[4];
#pragma unroll
        for (int nt = 0; nt < 4; nt++) {
            f32x4 a = (f32x4){0.f, 0.f, 0.f, 0.f};
#pragma unroll
            for (int ks = 0; ks < 2; ks++) {
                bf16x8 bk = *(const bf16x8*)(sK + (nt * 16 + l15) * 72 + ks * 32 + quad * 8);
                a = __builtin_amdgcn_mfma_f32_16x16x32_bf16(aq[ks], bk, a, 0, 0, 0);
            }
            s[nt] = a * scale;
        }
        // online softmax: row r_global = quad*4+r, cols spread over 16 lanes x 4 nt
        float alpha[4];
#pragma unroll
        for (int r = 0; r < 4; r++) {
            float mx = fmaxf(fmaxf(s[0][r], s[1][r]), fmaxf(s[2][r], s[3][r]));
#pragma unroll
            for (int msk = 1; msk < 16; msk <<= 1) mx = fmaxf(mx, __shfl_xor(mx, msk));
            float mnew = fmaxf(m_old[r], mx);
            alpha[r] = __expf(m_old[r] - mnew);
            float psum = 0.f;
#pragma unroll
            for (int nt = 0; nt < 4; nt++) {
                float p = __expf(s[nt][r] - mnew);
                s[nt][r] = p;
                psum += p;
            }
#pragma unroll
            for (int msk = 1; msk < 16; msk <<= 1) psum += __shfl_xor(psum, msk);
            l_sum[r] = l_sum[r] * alpha[r] + psum;
            m_old[r] = mnew;
        }
#pragma unroll
        for (int i = 0; i < 4; i++)
#pragma unroll
            for (int r = 0; r < 4; r++) oacc[i][r] *= alpha[r];
        // P: C-layout -> LDS -> A-layout (per-wave region)
#pragma unroll
        for (int nt = 0; nt < 4; nt++)
#pragma unroll
            for (int r = 0; r < 4; r++)
                sP[w * 1152 + (quad * 4 + r) * 72 + nt * 16 + l15] = f2b(s[nt][r]);
        __syncthreads();
        // O += P V
#pragma unroll
        for (int nt = 0; nt < 4; nt++) {
#pragma unroll
            for (int ks = 0; ks < 2; ks++) {
                bf16x8 ap = *(const bf16x8*)(sP + w * 1152 + l15 * 72 + ks * 32 + quad * 8);
                bf16x8 bv = *(const bf16x8*)(sV + (nt * 16 + l15) * 72 + ks * 32 + quad * 8);
                oacc[nt] = __builtin_amdgcn_mfma_f32_16x16x32_bf16(ap, bv, oacc[nt], 0, 0, 0);
            }
        }
    }
    // epilogue: o[b, seq, h*64+d]
    int b = bh >> 4, hh = bh & 15;
#pragma unroll
    for (int nt = 0; nt < 4; nt++)
#pragma unroll
        for (int r = 0; r < 4; r++) {
            int row = qt * 64 + w * 16 + quad * 4 + r;
            float val = oacc[nt][r] / l_sum[r];
            o[((size_t)b * 1024 + row) * 1024 + hh * 64 + nt * 16 + l15] = f2b(val);
        }
}

// ---------------------------------------------------------------- launch
// Workspace map (peak 20 MB — ub overlaps the dead q/k/vt/o buffers):
//   h   @  0 MB, 4 MB   (2048x1024 bf16)  — ln out, GEMM A operand
//   qb  @  4 MB, 4 MB   ([b,h,n,d] bf16)  — dead after attn
//   kb  @  8 MB, 4 MB                     — dead after attn
//   vtb @ 12 MB, 4 MB                     — dead after attn
//   ob  @ 16 MB, 4 MB                     — dead after out-proj
//   ub  @  4 MB, 16 MB  (2048x4096 bf16)  — mlp mid, live mlp1->mlp2 only
extern "C" void kernel_launch(void* const* d_in, const int* in_sizes, int n_in,
                              void* d_out, int out_size, void* d_ws, size_t ws_size,
                              hipStream_t stream) {
    const float* x = (const float*)d_in[0];
    const float* ln1_s = (const float*)d_in[1];
    const float* ln1_b = (const float*)d_in[2];
    const float* w_qkv = (const float*)d_in[3];
    const float* w_out = (const float*)d_in[4];
    const float* b_out = (const float*)d_in[5];
    const float* ln2_s = (const float*)d_in[6];
    const float* ln2_b = (const float*)d_in[7];
    const float* w1 = (const float*)d_in[8];
    const float* b1 = (const float*)d_in[9];
    const float* w2 = (const float*)d_in[10];
    const float* b2 = (const float*)d_in[11];

    float* res = (float*)d_out;  // residual lives in d_out (fp32, 2048x1024)
    char* wsb = (char*)d_ws;
    const size_t MB = 1024 * 1024;
    ushort_t* h = (ushort_t*)(wsb + 0 * MB);
    ushort_t* qb = (ushort_t*)(wsb + 4 * MB);
    ushort_t* kb = (ushort_t*)(wsb + 8 * MB);
    ushort_t* vtb = (ushort_t*)(wsb + 12 * MB);
    ushort_t* ob = (ushort_t*)(wsb + 16 * MB);
    ushort_t* ub = (ushort_t*)(wsb + 4 * MB);  // overlaps qb/kb/vtb/ob (all dead)

    copy_kernel<<<2048, 256, 0, stream>>>(x, res);
    for (int l = 0; l < 6; l++) {
        ln_kernel<<<2048, 256, 0, stream>>>(res, ln1_s + l * 1024, ln1_b + l * 1024, h);
        gemm_kernel<0><<<dim3(24, 16), 256, 0, stream>>>(
            h, w_qkv + (size_t)l * 1024 * 3072, nullptr, nullptr, nullptr, qb, kb, vtb,
            1024, 3072);
        attn_kernel<<<dim3(16, 32), 256, 0, stream>>>(qb, kb, vtb, ob);
        gemm_kernel<1><<<dim3(8, 16), 256, 0, stream>>>(
            ob, w_out + (size_t)l * 1024 * 1024, b_out + l * 1024, res, nullptr, nullptr,
            nullptr, nullptr, 1024, 1024);
        ln_kernel<<<2048, 256, 0, stream>>>(res, ln2_s + l * 1024, ln2_b + l * 1024, h);
        gemm_kernel<2><<<dim3(32, 16), 256, 0, stream>>>(
            h, w1 + (size_t)l * 1024 * 4096, b1 + l * 4096, nullptr, ub, nullptr, nullptr,
            nullptr, 1024, 4096);
        gemm_kernel<1><<<dim3(8, 16), 256, 0, stream>>>(
            ub, w2 + (size_t)l * 4096 * 1024, b2 + l * 1024, res, nullptr, nullptr,
            nullptr, nullptr, 4096, 1024);
    }
}

// Round 3
// 1703.425 us; speedup vs baseline: 2.0123x; 2.0123x over previous
//
#include <hip/hip_runtime.h>
#include <math.h>

typedef unsigned short ushort_t;
typedef __bf16 bf16x8 __attribute__((ext_vector_type(8)));
typedef float f32x4 __attribute__((ext_vector_type(4)));

#define HEADS 16

__device__ __forceinline__ ushort_t f2b(float f) {
    unsigned int u = __float_as_uint(f);
    unsigned int r = (u + 0x7FFFu + ((u >> 16) & 1u)) >> 16;
    return (ushort_t)r;
}

__device__ __forceinline__ void g2lds(const void* g, void* l) {
    __builtin_amdgcn_global_load_lds(
        (const __attribute__((address_space(1))) unsigned int*)g,
        (__attribute__((address_space(3))) unsigned int*)l, 16, 0, 0);
}

// ---------------------------------------------------------------- copy x -> residual
__global__ __launch_bounds__(256) void copy_kernel(const float* __restrict__ x,
                                                   float* __restrict__ y) {
    int i = blockIdx.x * 256 + threadIdx.x;
    ((float4*)y)[i] = ((const float4*)x)[i];
}

// ---------------------------------------------------------------- weight transpose+convert
// W fp32 [K,N] -> Wt bf16 [N,K]
__global__ __launch_bounds__(256) void transpose_kernel(const float* __restrict__ W,
                                                        ushort_t* __restrict__ Wt,
                                                        int K, int N) {
    __shared__ ushort_t sT[64 * 72];
    const int t = threadIdx.x;
    const int k0 = blockIdx.y * 64;
    const int n0 = blockIdx.x * 64;
    const int kk = t >> 4;          // 0..15
    const int nc = (t & 15) * 4;    // 0..60
#pragma unroll
    for (int i = 0; i < 4; i++) {
        int k = kk + i * 16;
        float4 v = *(const float4*)(W + (size_t)(k0 + k) * N + n0 + nc);
        const float* vf = (const float*)&v;
#pragma unroll
        for (int j = 0; j < 4; j++) sT[(nc + j) * 72 + k] = f2b(vf[j]);
    }
    __syncthreads();
#pragma unroll
    for (int p = 0; p < 2; p++) {
        int u = t + p * 256;
        int n = u >> 3;
        int kc = (u & 7) * 8;
        *(uint4*)(Wt + (size_t)(n0 + n) * K + k0 + kc) = *(const uint4*)(sT + n * 72 + kc);
    }
}

// ---------------------------------------------------------------- LayerNorm: fp32 res -> bf16 h
__global__ __launch_bounds__(256) void ln_kernel(const float* __restrict__ x,
                                                 const float* __restrict__ s,
                                                 const float* __restrict__ b,
                                                 ushort_t* __restrict__ out) {
    int row = blockIdx.x;
    int t = threadIdx.x;
    const float* xr = x + (size_t)row * 1024;
    float4 xv = *(const float4*)(xr + t * 4);
    float sum = xv.x + xv.y + xv.z + xv.w;
    float sq = xv.x * xv.x + xv.y * xv.y + xv.z * xv.z + xv.w * xv.w;
#pragma unroll
    for (int m = 1; m < 64; m <<= 1) {
        sum += __shfl_xor(sum, m);
        sq += __shfl_xor(sq, m);
    }
    __shared__ float red[8];
    int wave = t >> 6, lane = t & 63;
    if (lane == 0) { red[wave] = sum; red[4 + wave] = sq; }
    __syncthreads();
    sum = red[0] + red[1] + red[2] + red[3];
    sq = red[4] + red[5] + red[6] + red[7];
    float mean = sum * (1.0f / 1024.0f);
    float var = sq * (1.0f / 1024.0f) - mean * mean;
    float inv = rsqrtf(var + 1e-5f);
    float4 sv = *(const float4*)(s + t * 4);
    float4 bv = *(const float4*)(b + t * 4);
    unsigned int lo = (unsigned int)f2b((xv.x - mean) * inv * sv.x + bv.x) |
                      ((unsigned int)f2b((xv.y - mean) * inv * sv.y + bv.y) << 16);
    unsigned int hi = (unsigned int)f2b((xv.z - mean) * inv * sv.z + bv.z) |
                      ((unsigned int)f2b((xv.w - mean) * inv * sv.w + bv.w) << 16);
    uint2 o;
    o.x = lo; o.y = hi;
    *(uint2*)(out + (size_t)row * 1024 + t * 4) = o;
}

// ---------------------------------------------------------------- GEMM, m97 structure
// A bf16 [M,K] row-major, Bt bf16 [N,K] row-major, both staged via global_load_lds.
// Split-K over blockIdx.z (Ks = K / gridDim.z).
// MODE 0: QKV scatter -> q[b,h,n,d], k[b,h,n,d], vt[b,h,d,n] (bf16)
// MODE 1: res[m,n] += C + bias[n]  (atomic when gridDim.z > 1)
// MODE 2: outb[m,n] = bf16(gelu(C + bias[n]))
template <int MODE>
__global__ __launch_bounds__(256) void gemm_bt_kernel(
    const ushort_t* __restrict__ A, const ushort_t* __restrict__ Bt,
    const float* __restrict__ bias, float* __restrict__ res,
    ushort_t* __restrict__ outb, ushort_t* __restrict__ qo,
    ushort_t* __restrict__ ko, ushort_t* __restrict__ vto, int K, int N, int Ks) {
    // LDS: plain row-major [128 rows][32 k] bf16, 16B slot per (row, kchunk)
    __shared__ __align__(16) ushort_t sA[128 * 32];
    __shared__ __align__(16) ushort_t sB[128 * 32];
    const int t = threadIdx.x;
    const int lane = t & 63;
    const int wave = t >> 6;
    const int l15 = lane & 15;
    const int quad = lane >> 4;
    const int wm = wave >> 1, wn = wave & 1;
    const int m0 = blockIdx.y * 128;
    const int n0 = blockIdx.x * 128;
    const int kbeg = blockIdx.z * Ks;

    f32x4 acc[4][4];
#pragma unroll
    for (int i = 0; i < 4; i++)
#pragma unroll
        for (int j = 0; j < 4; j++) acc[i][j] = (f32x4){0.f, 0.f, 0.f, 0.f};

    // staging: slot u = p*256 + t; row = u>>2, kchunk = u&3; lane writes base+lane*16B
    const int r0 = t >> 2, c8 = (t & 3) * 8;
    const ushort_t* gA0 = A + (size_t)(m0 + r0) * K + kbeg + c8;
    const ushort_t* gA1 = A + (size_t)(m0 + 64 + r0) * K + kbeg + c8;
    const ushort_t* gB0 = Bt + (size_t)(n0 + r0) * K + kbeg + c8;
    const ushort_t* gB1 = Bt + (size_t)(n0 + 64 + r0) * K + kbeg + c8;
    ushort_t* lA0 = sA + (wave * 64) * 8;        // wave-uniform LDS bases
    ushort_t* lA1 = sA + (256 + wave * 64) * 8;
    ushort_t* lB0 = sB + (wave * 64) * 8;
    ushort_t* lB1 = sB + (256 + wave * 64) * 8;

    const int nkt = Ks >> 5;
    for (int kt = 0; kt < nkt; kt++) {
        const int ko_off = kt * 32;
        __syncthreads();
        g2lds(gA0 + ko_off, lA0);
        g2lds(gA1 + ko_off, lA1);
        g2lds(gB0 + ko_off, lB0);
        g2lds(gB1 + ko_off, lB1);
        __syncthreads();
        bf16x8 af[4], bf[4];
#pragma unroll
        for (int i = 0; i < 4; i++) {
            af[i] = *(const bf16x8*)(sA + ((wm * 64 + i * 16 + l15) * 4 + quad) * 8);
            bf[i] = *(const bf16x8*)(sB + ((wn * 64 + i * 16 + l15) * 4 + quad) * 8);
        }
#pragma unroll
        for (int mi = 0; mi < 4; mi++)
#pragma unroll
            for (int ni = 0; ni < 4; ni++)
                acc[mi][ni] = __builtin_amdgcn_mfma_f32_16x16x32_bf16(
                    af[mi], bf[ni], acc[mi][ni], 0, 0, 0);
    }
    // epilogue: C/D layout row = quad*4+r, col = l15
#pragma unroll
    for (int mi = 0; mi < 4; mi++) {
#pragma unroll
        for (int ni = 0; ni < 4; ni++) {
#pragma unroll
            for (int r = 0; r < 4; r++) {
                int mg = m0 + wm * 64 + mi * 16 + quad * 4 + r;
                int ng = n0 + wn * 64 + ni * 16 + l15;
                float c = acc[mi][ni][r];
                if (MODE == 1) {
                    size_t idx = (size_t)mg * N + ng;
                    float add = c + (kbeg == 0 ? bias[ng] : 0.f);
                    if (gridDim.z > 1)
                        atomicAdd(&res[idx], add);
                    else
                        res[idx] = res[idx] + add;
                } else if (MODE == 2) {
                    float vv = c + bias[ng];
                    float g = 0.5f * vv * (1.0f + erff(vv * 0.70710678118654752f));
                    outb[(size_t)mg * N + ng] = f2b(g);
                } else {
                    int qkv = ng >> 10;
                    int rem = ng & 1023;
                    int hh = rem >> 6;
                    int dd = rem & 63;
                    int bb = mg >> 10;
                    int seq = mg & 1023;
                    ushort_t val = f2b(c);
                    if (qkv == 0)
                        qo[((size_t)(bb * HEADS + hh) * 1024 + seq) * 64 + dd] = val;
                    else if (qkv == 1)
                        ko[((size_t)(bb * HEADS + hh) * 1024 + seq) * 64 + dd] = val;
                    else
                        vto[((size_t)(bb * HEADS + hh) * 64 + dd) * 1024 + seq] = val;
                }
            }
        }
    }
}

// ---------------------------------------------------------------- flash attention
// q,k: [b,h,1024,64] bf16; vt: [b,h,64,1024] bf16; o: [b,1024,1024] bf16 (seq-major, feat=h*64+d)
__global__ __launch_bounds__(256) void attn_kernel(const ushort_t* __restrict__ q,
                                                   const ushort_t* __restrict__ k,
                                                   const ushort_t* __restrict__ vt,
                                                   ushort_t* __restrict__ o) {
    __shared__ __align__(16) ushort_t sK[64 * 72];
    __shared__ __align__(16) ushort_t sV[64 * 72];
    __shared__ __align__(16) ushort_t sP[4 * 16 * 72];
    const int t = threadIdx.x;
    const int lane = t & 63;
    const int w = t >> 6;
    const int l15 = lane & 15;
    const int quad = lane >> 4;
    const int qt = blockIdx.x;
    const int bh = blockIdx.y;

    bf16x8 aq[2];
    const ushort_t* qbase = q + ((size_t)bh * 1024 + qt * 64 + w * 16 + l15) * 64;
    aq[0] = *(const bf16x8*)(qbase + quad * 8);
    aq[1] = *(const bf16x8*)(qbase + 32 + quad * 8);

    float m_old[4], l_sum[4];
    f32x4 oacc[4];
#pragma unroll
    for (int r = 0; r < 4; r++) { m_old[r] = -1e30f; l_sum[r] = 0.f; }
#pragma unroll
    for (int i = 0; i < 4; i++) oacc[i] = (f32x4){0.f, 0.f, 0.f, 0.f};

    const float scale = 0.03125f;  // 1024^-0.5 (reference scales by full D!)

    for (int kt = 0; kt < 16; kt++) {
        __syncthreads();
#pragma unroll
        for (int p = 0; p < 2; p++) {
            int u = t + p * 256;
            int row = u >> 3, ch = u & 7;
            uint4 v = *(const uint4*)(k + ((size_t)bh * 1024 + kt * 64 + row) * 64 + ch * 8);
            *(uint4*)(sK + row * 72 + ch * 8) = v;
            uint4 v2 = *(const uint4*)(vt + ((size_t)bh * 64 + row) * 1024 + kt * 64 + ch * 8);
            *(uint4*)(sV + row * 72 + ch * 8) = v2;
        }
        __syncthreads();
        f32x4 s[4];
#pragma unroll
        for (int nt = 0; nt < 4; nt++) {
            f32x4 a = (f32x4){0.f, 0.f, 0.f, 0.f};
#pragma unroll
            for (int ks = 0; ks < 2; ks++) {
                bf16x8 bk = *(const bf16x8*)(sK + (nt * 16 + l15) * 72 + ks * 32 + quad * 8);
                a = __builtin_amdgcn_mfma_f32_16x16x32_bf16(aq[ks], bk, a, 0, 0, 0);
            }
            s[nt] = a * scale;
        }
        float alpha[4];
#pragma unroll
        for (int r = 0; r < 4; r++) {
            float mx = fmaxf(fmaxf(s[0][r], s[1][r]), fmaxf(s[2][r], s[3][r]));
#pragma unroll
            for (int msk = 1; msk < 16; msk <<= 1) mx = fmaxf(mx, __shfl_xor(mx, msk));
            float mnew = fmaxf(m_old[r], mx);
            alpha[r] = __expf(m_old[r] - mnew);
            float psum = 0.f;
#pragma unroll
            for (int nt = 0; nt < 4; nt++) {
                float p = __expf(s[nt][r] - mnew);
                s[nt][r] = p;
                psum += p;
            }
#pragma unroll
            for (int msk = 1; msk < 16; msk <<= 1) psum += __shfl_xor(psum, msk);
            l_sum[r] = l_sum[r] * alpha[r] + psum;
            m_old[r] = mnew;
        }
#pragma unroll
        for (int i = 0; i < 4; i++)
#pragma unroll
            for (int r = 0; r < 4; r++) oacc[i][r] *= alpha[r];
#pragma unroll
        for (int nt = 0; nt < 4; nt++)
#pragma unroll
            for (int r = 0; r < 4; r++)
                sP[w * 1152 + (quad * 4 + r) * 72 + nt * 16 + l15] = f2b(s[nt][r]);
        __syncthreads();
#pragma unroll
        for (int nt = 0; nt < 4; nt++) {
#pragma unroll
            for (int ks = 0; ks < 2; ks++) {
                bf16x8 ap = *(const bf16x8*)(sP + w * 1152 + l15 * 72 + ks * 32 + quad * 8);
                bf16x8 bv = *(const bf16x8*)(sV + (nt * 16 + l15) * 72 + ks * 32 + quad * 8);
                oacc[nt] = __builtin_amdgcn_mfma_f32_16x16x32_bf16(ap, bv, oacc[nt], 0, 0, 0);
            }
        }
    }
    int b = bh >> 4, hh = bh & 15;
#pragma unroll
    for (int nt = 0; nt < 4; nt++)
#pragma unroll
        for (int r = 0; r < 4; r++) {
            int row = qt * 64 + w * 16 + quad * 4 + r;
            float val = oacc[nt][r] / l_sum[r];
            o[((size_t)b * 1024 + row) * 1024 + hh * 64 + nt * 16 + l15] = f2b(val);
        }
}

// ---------------------------------------------------------------- launch
// ws map (peak 28 MB):
//   h    @  0 MB (4)   ln out / GEMM A
//   qb   @  4 MB (4), kb @ 8 (4), vtb @ 12 (4), ob @ 16 (4)  — attn phase
//   ub   @  4 MB (16)  mlp mid (overlaps dead q/k/vt/o)
//   wbuf @ 20 MB (8): wqkv_t@20(6) + wo_t@26(2); later w1_t@20(8); later w2_t@20(8)
extern "C" void kernel_launch(void* const* d_in, const int* in_sizes, int n_in,
                              void* d_out, int out_size, void* d_ws, size_t ws_size,
                              hipStream_t stream) {
    const float* x = (const float*)d_in[0];
    const float* ln1_s = (const float*)d_in[1];
    const float* ln1_b = (const float*)d_in[2];
    const float* w_qkv = (const float*)d_in[3];
    const float* w_out = (const float*)d_in[4];
    const float* b_out = (const float*)d_in[5];
    const float* ln2_s = (const float*)d_in[6];
    const float* ln2_b = (const float*)d_in[7];
    const float* w1 = (const float*)d_in[8];
    const float* b1 = (const float*)d_in[9];
    const float* w2 = (const float*)d_in[10];
    const float* b2 = (const float*)d_in[11];

    float* res = (float*)d_out;
    char* wsb = (char*)d_ws;
    const size_t MB = 1024 * 1024;
    ushort_t* h = (ushort_t*)(wsb + 0 * MB);
    ushort_t* qb = (ushort_t*)(wsb + 4 * MB);
    ushort_t* kb = (ushort_t*)(wsb + 8 * MB);
    ushort_t* vtb = (ushort_t*)(wsb + 12 * MB);
    ushort_t* ob = (ushort_t*)(wsb + 16 * MB);
    ushort_t* ub = (ushort_t*)(wsb + 4 * MB);
    ushort_t* wqkv_t = (ushort_t*)(wsb + 20 * MB);
    ushort_t* wo_t = (ushort_t*)(wsb + 26 * MB);
    ushort_t* w12_t = (ushort_t*)(wsb + 20 * MB);

    copy_kernel<<<2048, 256, 0, stream>>>(x, res);
    for (int l = 0; l < 6; l++) {
        transpose_kernel<<<dim3(48, 16), 256, 0, stream>>>(
            w_qkv + (size_t)l * 1024 * 3072, wqkv_t, 1024, 3072);
        transpose_kernel<<<dim3(16, 16), 256, 0, stream>>>(
            w_out + (size_t)l * 1024 * 1024, wo_t, 1024, 1024);
        ln_kernel<<<2048, 256, 0, stream>>>(res, ln1_s + l * 1024, ln1_b + l * 1024, h);
        gemm_bt_kernel<0><<<dim3(24, 16, 1), 256, 0, stream>>>(
            h, wqkv_t, nullptr, nullptr, nullptr, qb, kb, vtb, 1024, 3072, 1024);
        attn_kernel<<<dim3(16, 32), 256, 0, stream>>>(qb, kb, vtb, ob);
        gemm_bt_kernel<1><<<dim3(8, 16, 2), 256, 0, stream>>>(
            ob, wo_t, b_out + l * 1024, res, nullptr, nullptr, nullptr, nullptr,
            1024, 1024, 512);
        transpose_kernel<<<dim3(64, 16), 256, 0, stream>>>(
            w1 + (size_t)l * 1024 * 4096, w12_t, 1024, 4096);
        ln_kernel<<<2048, 256, 0, stream>>>(res, ln2_s + l * 1024, ln2_b + l * 1024, h);
        gemm_bt_kernel<2><<<dim3(32, 16, 1), 256, 0, stream>>>(
            h, w12_t, b1 + l * 4096, nullptr, ub, nullptr, nullptr, nullptr,
            1024, 4096, 1024);
        transpose_kernel<<<dim3(16, 64), 256, 0, stream>>>(
            w2 + (size_t)l * 4096 * 1024, w12_t, 4096, 1024);
        gemm_bt_kernel<1><<<dim3(8, 16, 4), 256, 0, stream>>>(
            ub, w12_t, b2 + l * 1024, res, nullptr, nullptr, nullptr, nullptr,
            4096, 1024, 1024);
    }
}

// Round 4
// 1616.455 us; speedup vs baseline: 2.1205x; 1.0538x over previous
//
#include <hip/hip_runtime.h>
#include <math.h>

typedef unsigned short ushort_t;
typedef __bf16 bf16x8 __attribute__((ext_vector_type(8)));
typedef float f32x4 __attribute__((ext_vector_type(4)));

#define HEADS 16

__device__ __forceinline__ ushort_t f2b(float f) {
    unsigned int u = __float_as_uint(f);
    unsigned int r = (u + 0x7FFFu + ((u >> 16) & 1u)) >> 16;
    return (ushort_t)r;
}

__device__ __forceinline__ void g2lds(const void* g, void* l) {
    __builtin_amdgcn_global_load_lds(
        (const __attribute__((address_space(1))) unsigned int*)g,
        (__attribute__((address_space(3))) unsigned int*)l, 16, 0, 0);
}

// ---------------------------------------------------------------- copy x -> residual
__global__ __launch_bounds__(256) void copy_kernel(const float* __restrict__ x,
                                                   float* __restrict__ y) {
    int i = blockIdx.x * 256 + threadIdx.x;
    ((float4*)y)[i] = ((const float4*)x)[i];
}

// ---------------------------------------------------------------- weight transpose+convert
// W fp32 [K,N] -> Wt bf16 [N,K]
__global__ __launch_bounds__(256) void transpose_kernel(const float* __restrict__ W,
                                                        ushort_t* __restrict__ Wt,
                                                        int K, int N) {
    __shared__ ushort_t sT[64 * 72];
    const int t = threadIdx.x;
    const int k0 = blockIdx.y * 64;
    const int n0 = blockIdx.x * 64;
    const int kk = t >> 4;          // 0..15
    const int nc = (t & 15) * 4;    // 0..60
#pragma unroll
    for (int i = 0; i < 4; i++) {
        int k = kk + i * 16;
        float4 v = *(const float4*)(W + (size_t)(k0 + k) * N + n0 + nc);
        const float* vf = (const float*)&v;
#pragma unroll
        for (int j = 0; j < 4; j++) sT[(nc + j) * 72 + k] = f2b(vf[j]);
    }
    __syncthreads();
#pragma unroll
    for (int p = 0; p < 2; p++) {
        int u = t + p * 256;
        int n = u >> 3;
        int kc = (u & 7) * 8;
        *(uint4*)(Wt + (size_t)(n0 + n) * K + k0 + kc) = *(const uint4*)(sT + n * 72 + kc);
    }
}

// ---------------------------------------------------------------- LayerNorm: fp32 res -> bf16 h
__global__ __launch_bounds__(256) void ln_kernel(const float* __restrict__ x,
                                                 const float* __restrict__ s,
                                                 const float* __restrict__ b,
                                                 ushort_t* __restrict__ out) {
    int row = blockIdx.x;
    int t = threadIdx.x;
    const float* xr = x + (size_t)row * 1024;
    float4 xv = *(const float4*)(xr + t * 4);
    float sum = xv.x + xv.y + xv.z + xv.w;
    float sq = xv.x * xv.x + xv.y * xv.y + xv.z * xv.z + xv.w * xv.w;
#pragma unroll
    for (int m = 1; m < 64; m <<= 1) {
        sum += __shfl_xor(sum, m);
        sq += __shfl_xor(sq, m);
    }
    __shared__ float red[8];
    int wave = t >> 6, lane = t & 63;
    if (lane == 0) { red[wave] = sum; red[4 + wave] = sq; }
    __syncthreads();
    sum = red[0] + red[1] + red[2] + red[3];
    sq = red[4] + red[5] + red[6] + red[7];
    float mean = sum * (1.0f / 1024.0f);
    float var = sq * (1.0f / 1024.0f) - mean * mean;
    float inv = rsqrtf(var + 1e-5f);
    float4 sv = *(const float4*)(s + t * 4);
    float4 bv = *(const float4*)(b + t * 4);
    unsigned int lo = (unsigned int)f2b((xv.x - mean) * inv * sv.x + bv.x) |
                      ((unsigned int)f2b((xv.y - mean) * inv * sv.y + bv.y) << 16);
    unsigned int hi = (unsigned int)f2b((xv.z - mean) * inv * sv.z + bv.z) |
                      ((unsigned int)f2b((xv.w - mean) * inv * sv.w + bv.w) << 16);
    uint2 o;
    o.x = lo; o.y = hi;
    *(uint2*)(out + (size_t)row * 1024 + t * 4) = o;
}

// ---------------------------------------------------------------- GEMM, m97 structure, BK=64
// A bf16 [M,K] row-major, Bt bf16 [N,K] row-major, staged via global_load_lds with
// XOR-swizzled k-chunks (chunk_phys c holds global chunk c ^ (row&7)) so BK=64 frag
// reads spread across all 32 banks (2-way aliasing only).
// Split-K over blockIdx.z (Ks = K / gridDim.z).
// MODE 0: QKV scatter -> q[b,h,n,d], k[b,h,n,d], vt[b,h,d,n] (bf16)
// MODE 1: res[m,n] += C + bias[n]  (atomic when gridDim.z > 1)
// MODE 2: outb[m,n] = bf16(gelu(C + bias[n]))
template <int MODE>
__global__ __launch_bounds__(256) void gemm_bt_kernel(
    const ushort_t* __restrict__ A, const ushort_t* __restrict__ Bt,
    const float* __restrict__ bias, float* __restrict__ res,
    ushort_t* __restrict__ outb, ushort_t* __restrict__ qo,
    ushort_t* __restrict__ ko, ushort_t* __restrict__ vto, int K, int N, int Ks) {
    __shared__ __align__(16) ushort_t sA[128 * 64];  // 16 KB
    __shared__ __align__(16) ushort_t sB[128 * 64];  // 16 KB
    const int t = threadIdx.x;
    const int lane = t & 63;
    const int wave = t >> 6;
    const int l15 = lane & 15;
    const int quad = lane >> 4;
    const int wm = wave >> 1, wn = wave & 1;
    const int m0 = blockIdx.y * 128;
    const int n0 = blockIdx.x * 128;
    const int kbeg = blockIdx.z * Ks;

    f32x4 acc[4][4];
#pragma unroll
    for (int i = 0; i < 4; i++)
#pragma unroll
        for (int j = 0; j < 4; j++) acc[i][j] = (f32x4){0.f, 0.f, 0.f, 0.f};

    // staging: slot u = p*256 + wave*64 + lane; row = u>>3, c_phys = u&7 = lane&7;
    // global chunk = c_phys ^ (row&7), row&7 = lane>>3.
    const int rlow = lane >> 3;
    const int chunk = (lane & 7) ^ rlow;
    const int rowS = wave * 8 + rlow;  // + p*32
    const ushort_t* gA = A + (size_t)(m0 + rowS) * K + kbeg + chunk * 8;
    const ushort_t* gB = Bt + (size_t)(n0 + rowS) * K + kbeg + chunk * 8;
    ushort_t* lA = sA + wave * 64 * 8;  // + p*2048 (wave-uniform)
    ushort_t* lB = sB + wave * 64 * 8;
    const int xorv = l15 & 7;

    const int nkt = Ks >> 6;
    for (int kt = 0; kt < nkt; kt++) {
        const size_t koff = (size_t)kt * 64;
        __syncthreads();
#pragma unroll
        for (int p = 0; p < 4; p++) {
            g2lds(gA + (size_t)p * 32 * K + koff, lA + p * 2048);
            g2lds(gB + (size_t)p * 32 * K + koff, lB + p * 2048);
        }
        __syncthreads();
#pragma unroll
        for (int ks = 0; ks < 2; ks++) {
            const int co = ((ks * 4 + quad) ^ xorv) * 8;
            bf16x8 af[4], bf[4];
#pragma unroll
            for (int i = 0; i < 4; i++) {
                af[i] = *(const bf16x8*)(sA + (wm * 64 + i * 16 + l15) * 64 + co);
                bf[i] = *(const bf16x8*)(sB + (wn * 64 + i * 16 + l15) * 64 + co);
            }
#pragma unroll
            for (int mi = 0; mi < 4; mi++)
#pragma unroll
                for (int ni = 0; ni < 4; ni++)
                    acc[mi][ni] = __builtin_amdgcn_mfma_f32_16x16x32_bf16(
                        af[mi], bf[ni], acc[mi][ni], 0, 0, 0);
        }
    }
    // epilogue: C/D layout row = quad*4+r, col = l15
#pragma unroll
    for (int mi = 0; mi < 4; mi++) {
#pragma unroll
        for (int ni = 0; ni < 4; ni++) {
#pragma unroll
            for (int r = 0; r < 4; r++) {
                int mg = m0 + wm * 64 + mi * 16 + quad * 4 + r;
                int ng = n0 + wn * 64 + ni * 16 + l15;
                float c = acc[mi][ni][r];
                if (MODE == 1) {
                    size_t idx = (size_t)mg * N + ng;
                    float add = c + (kbeg == 0 ? bias[ng] : 0.f);
                    if (gridDim.z > 1)
                        atomicAdd(&res[idx], add);
                    else
                        res[idx] = res[idx] + add;
                } else if (MODE == 2) {
                    float vv = c + bias[ng];
                    float g = 0.5f * vv * (1.0f + erff(vv * 0.70710678118654752f));
                    outb[(size_t)mg * N + ng] = f2b(g);
                } else {
                    int qkv = ng >> 10;
                    int rem = ng & 1023;
                    int hh = rem >> 6;
                    int dd = rem & 63;
                    int bb = mg >> 10;
                    int seq = mg & 1023;
                    ushort_t val = f2b(c);
                    if (qkv == 0)
                        qo[((size_t)(bb * HEADS + hh) * 1024 + seq) * 64 + dd] = val;
                    else if (qkv == 1)
                        ko[((size_t)(bb * HEADS + hh) * 1024 + seq) * 64 + dd] = val;
                    else
                        vto[((size_t)(bb * HEADS + hh) * 64 + dd) * 1024 + seq] = val;
                }
            }
        }
    }
}

// ---------------------------------------------------------------- flash attention
// q,k: [b,h,1024,64] bf16; vt: [b,h,64,1024] bf16; o: [b,1024,1024] bf16 (seq-major, feat=h*64+d)
__global__ __launch_bounds__(256) void attn_kernel(const ushort_t* __restrict__ q,
                                                   const ushort_t* __restrict__ k,
                                                   const ushort_t* __restrict__ vt,
                                                   ushort_t* __restrict__ o) {
    __shared__ __align__(16) ushort_t sK[64 * 72];
    __shared__ __align__(16) ushort_t sV[64 * 72];
    __shared__ __align__(16) ushort_t sP[4 * 16 * 72];
    const int t = threadIdx.x;
    const int lane = t & 63;
    const int w = t >> 6;
    const int l15 = lane & 15;
    const int quad = lane >> 4;
    const int qt = blockIdx.x;
    const int bh = blockIdx.y;

    bf16x8 aq[2];
    const ushort_t* qbase = q + ((size_t)bh * 1024 + qt * 64 + w * 16 + l15) * 64;
    aq[0] = *(const bf16x8*)(qbase + quad * 8);
    aq[1] = *(const bf16x8*)(qbase + 32 + quad * 8);

    float m_old[4], l_sum[4];
    f32x4 oacc[4];
#pragma unroll
    for (int r = 0; r < 4; r++) { m_old[r] = -1e30f; l_sum[r] = 0.f; }
#pragma unroll
    for (int i = 0; i < 4; i++) oacc[i] = (f32x4){0.f, 0.f, 0.f, 0.f};

    const float scale = 0.03125f;  // 1024^-0.5 (reference scales by full D!)

    for (int kt = 0; kt < 16; kt++) {
        __syncthreads();
#pragma unroll
        for (int p = 0; p < 2; p++) {
            int u = t + p * 256;
            int row = u >> 3, ch = u & 7;
            uint4 v = *(const uint4*)(k + ((size_t)bh * 1024 + kt * 64 + row) * 64 + ch * 8);
            *(uint4*)(sK + row * 72 + ch * 8) = v;
            uint4 v2 = *(const uint4*)(vt + ((size_t)bh * 64 + row) * 1024 + kt * 64 + ch * 8);
            *(uint4*)(sV + row * 72 + ch * 8) = v2;
        }
        __syncthreads();
        f32x4 s[4];
#pragma unroll
        for (int nt = 0; nt < 4; nt++) {
            f32x4 a = (f32x4){0.f, 0.f, 0.f, 0.f};
#pragma unroll
            for (int ks = 0; ks < 2; ks++) {
                bf16x8 bk = *(const bf16x8*)(sK + (nt * 16 + l15) * 72 + ks * 32 + quad * 8);
                a = __builtin_amdgcn_mfma_f32_16x16x32_bf16(aq[ks], bk, a, 0, 0, 0);
            }
            s[nt] = a * scale;
        }
        float alpha[4];
#pragma unroll
        for (int r = 0; r < 4; r++) {
            float mx = fmaxf(fmaxf(s[0][r], s[1][r]), fmaxf(s[2][r], s[3][r]));
#pragma unroll
            for (int msk = 1; msk < 16; msk <<= 1) mx = fmaxf(mx, __shfl_xor(mx, msk));
            float mnew = fmaxf(m_old[r], mx);
            alpha[r] = __expf(m_old[r] - mnew);
            float psum = 0.f;
#pragma unroll
            for (int nt = 0; nt < 4; nt++) {
                float p = __expf(s[nt][r] - mnew);
                s[nt][r] = p;
                psum += p;
            }
#pragma unroll
            for (int msk = 1; msk < 16; msk <<= 1) psum += __shfl_xor(psum, msk);
            l_sum[r] = l_sum[r] * alpha[r] + psum;
            m_old[r] = mnew;
        }
#pragma unroll
        for (int i = 0; i < 4; i++)
#pragma unroll
            for (int r = 0; r < 4; r++) oacc[i][r] *= alpha[r];
#pragma unroll
        for (int nt = 0; nt < 4; nt++)
#pragma unroll
            for (int r = 0; r < 4; r++)
                sP[w * 1152 + (quad * 4 + r) * 72 + nt * 16 + l15] = f2b(s[nt][r]);
        __syncthreads();
#pragma unroll
        for (int nt = 0; nt < 4; nt++) {
#pragma unroll
            for (int ks = 0; ks < 2; ks++) {
                bf16x8 ap = *(const bf16x8*)(sP + w * 1152 + l15 * 72 + ks * 32 + quad * 8);
                bf16x8 bv = *(const bf16x8*)(sV + (nt * 16 + l15) * 72 + ks * 32 + quad * 8);
                oacc[nt] = __builtin_amdgcn_mfma_f32_16x16x32_bf16(ap, bv, oacc[nt], 0, 0, 0);
            }
        }
    }
    int b = bh >> 4, hh = bh & 15;
#pragma unroll
    for (int nt = 0; nt < 4; nt++)
#pragma unroll
        for (int r = 0; r < 4; r++) {
            int row = qt * 64 + w * 16 + quad * 4 + r;
            float val = oacc[nt][r] / l_sum[r];
            o[((size_t)b * 1024 + row) * 1024 + hh * 64 + nt * 16 + l15] = f2b(val);
        }
}

// ---------------------------------------------------------------- launch
// ws map (peak 28 MB):
//   h    @  0 MB (4)   ln out / GEMM A
//   qb   @  4 MB (4), kb @ 8 (4), vtb @ 12 (4), ob @ 16 (4)  — attn phase
//   ub   @  4 MB (16)  mlp mid (overlaps dead q/k/vt/o)
//   wbuf @ 20 MB (8): wqkv_t@20(6) + wo_t@26(2); later w1_t@20(8); later w2_t@20(8)
extern "C" void kernel_launch(void* const* d_in, const int* in_sizes, int n_in,
                              void* d_out, int out_size, void* d_ws, size_t ws_size,
                              hipStream_t stream) {
    const float* x = (const float*)d_in[0];
    const float* ln1_s = (const float*)d_in[1];
    const float* ln1_b = (const float*)d_in[2];
    const float* w_qkv = (const float*)d_in[3];
    const float* w_out = (const float*)d_in[4];
    const float* b_out = (const float*)d_in[5];
    const float* ln2_s = (const float*)d_in[6];
    const float* ln2_b = (const float*)d_in[7];
    const float* w1 = (const float*)d_in[8];
    const float* b1 = (const float*)d_in[9];
    const float* w2 = (const float*)d_in[10];
    const float* b2 = (const float*)d_in[11];

    float* res = (float*)d_out;
    char* wsb = (char*)d_ws;
    const size_t MB = 1024 * 1024;
    ushort_t* h = (ushort_t*)(wsb + 0 * MB);
    ushort_t* qb = (ushort_t*)(wsb + 4 * MB);
    ushort_t* kb = (ushort_t*)(wsb + 8 * MB);
    ushort_t* vtb = (ushort_t*)(wsb + 12 * MB);
    ushort_t* ob = (ushort_t*)(wsb + 16 * MB);
    ushort_t* ub = (ushort_t*)(wsb + 4 * MB);
    ushort_t* wqkv_t = (ushort_t*)(wsb + 20 * MB);
    ushort_t* wo_t = (ushort_t*)(wsb + 26 * MB);
    ushort_t* w12_t = (ushort_t*)(wsb + 20 * MB);

    copy_kernel<<<2048, 256, 0, stream>>>(x, res);
    for (int l = 0; l < 6; l++) {
        transpose_kernel<<<dim3(48, 16), 256, 0, stream>>>(
            w_qkv + (size_t)l * 1024 * 3072, wqkv_t, 1024, 3072);
        transpose_kernel<<<dim3(16, 16), 256, 0, stream>>>(
            w_out + (size_t)l * 1024 * 1024, wo_t, 1024, 1024);
        ln_kernel<<<2048, 256, 0, stream>>>(res, ln1_s + l * 1024, ln1_b + l * 1024, h);
        gemm_bt_kernel<0><<<dim3(24, 16, 1), 256, 0, stream>>>(
            h, wqkv_t, nullptr, nullptr, nullptr, qb, kb, vtb, 1024, 3072, 1024);
        attn_kernel<<<dim3(16, 32), 256, 0, stream>>>(qb, kb, vtb, ob);
        gemm_bt_kernel<1><<<dim3(8, 16, 4), 256, 0, stream>>>(
            ob, wo_t, b_out + l * 1024, res, nullptr, nullptr, nullptr, nullptr,
            1024, 1024, 256);
        transpose_kernel<<<dim3(64, 16), 256, 0, stream>>>(
            w1 + (size_t)l * 1024 * 4096, w12_t, 1024, 4096);
        ln_kernel<<<2048, 256, 0, stream>>>(res, ln2_s + l * 1024, ln2_b + l * 1024, h);
        gemm_bt_kernel<2><<<dim3(32, 16, 1), 256, 0, stream>>>(
            h, w12_t, b1 + l * 4096, nullptr, ub, nullptr, nullptr, nullptr,
            1024, 4096, 1024);
        transpose_kernel<<<dim3(16, 64), 256, 0, stream>>>(
            w2 + (size_t)l * 4096 * 1024, w12_t, 4096, 1024);
        gemm_bt_kernel<1><<<dim3(8, 16, 4), 256, 0, stream>>>(
            ub, w12_t, b2 + l * 1024, res, nullptr, nullptr, nullptr, nullptr,
            4096, 1024, 1024);
    }
}